// Round 1
// baseline (3297.504 us; speedup 1.0000x reference)
//
#include <hip/hip_runtime.h>

#define N_NODES 100000
#define N_EDGES 1200000
#define HDIM 64
#define NUM_RELS 24

// ---------------- histogram of rel (24 bins) ----------------
__global__ void hist_kernel(const int* __restrict__ rel, int* __restrict__ cnt) {
    __shared__ int lc[NUM_RELS];
    if (threadIdx.x < NUM_RELS) lc[threadIdx.x] = 0;
    __syncthreads();
    for (int i = blockIdx.x * blockDim.x + threadIdx.x; i < N_EDGES;
         i += gridDim.x * blockDim.x)
        atomicAdd(&lc[rel[i]], 1);
    __syncthreads();
    if (threadIdx.x < NUM_RELS) atomicAdd(&cnt[threadIdx.x], lc[threadIdx.x]);
}

// ---------------- exclusive scan of 24 bins (1 thread) ----------------
__global__ void scan_kernel(const int* __restrict__ cnt, int* __restrict__ ofs) {
    if (threadIdx.x == 0 && blockIdx.x == 0) {
        int acc = 0;
        for (int r = 0; r < NUM_RELS; ++r) { ofs[r] = acc; acc += cnt[r]; }
    }
}

// ---------------- scatter into rel-sorted order + degree ----------------
__global__ void scatter_kernel(const int* __restrict__ src, const int* __restrict__ dst,
                               const int* __restrict__ rel, int* __restrict__ ofs,
                               int* __restrict__ ssrc, int* __restrict__ sdst,
                               int* __restrict__ srel, float* __restrict__ deg) {
    for (int i = blockIdx.x * blockDim.x + threadIdx.x; i < N_EDGES;
         i += gridDim.x * blockDim.x) {
        int r = rel[i];
        int p = atomicAdd(&ofs[r], 1);
        ssrc[p] = src[i];
        sdst[p] = dst[i];
        srel[p] = r;
        atomicAdd(&deg[dst[i]], 1.0f);
    }
}

// ---------------- per-edge transform + scatter-add ----------------
// One wave per contiguous chunk of rel-sorted edges. Lane j keeps column j of
// W[r] in registers (64 VGPR); h[src] is wave-uniform (broadcast float4 loads).
__global__ __launch_bounds__(256) void edge_kernel(
    const float* __restrict__ hin, const int* __restrict__ ssrc,
    const int* __restrict__ sdst, const int* __restrict__ srel,
    const float* __restrict__ W, float* __restrict__ agg) {
    const int lane = threadIdx.x & 63;
    const int wid = blockIdx.x * (blockDim.x >> 6) + (threadIdx.x >> 6);
    const int nw = gridDim.x * (blockDim.x >> 6);
    const int per = (N_EDGES + nw - 1) / nw;
    int lo = wid * per;
    int hi = lo + per;
    if (hi > N_EDGES) hi = N_EDGES;
    if (lo >= hi) return;

    float wcol[HDIM];
    int cur_r = -1;
    for (int e = lo; e < hi; ++e) {
        int r = __builtin_amdgcn_readfirstlane(srel[e]);
        int s = __builtin_amdgcn_readfirstlane(ssrc[e]);
        int d = __builtin_amdgcn_readfirstlane(sdst[e]);
        if (r != cur_r) {  // wave-uniform branch; ~1 reload per chunk
            cur_r = r;
            const float* wp = W + (size_t)r * (HDIM * HDIM) + lane;
#pragma unroll
            for (int k = 0; k < HDIM; ++k) wcol[k] = wp[(size_t)k * HDIM];
        }
        const float4* hp = (const float4*)(hin + (size_t)s * HDIM);
        float acc = 0.f;
#pragma unroll
        for (int q = 0; q < HDIM / 4; ++q) {
            float4 hv = hp[q];
            acc = fmaf(hv.x, wcol[4 * q + 0], acc);
            acc = fmaf(hv.y, wcol[4 * q + 1], acc);
            acc = fmaf(hv.z, wcol[4 * q + 2], acc);
            acc = fmaf(hv.w, wcol[4 * q + 3], acc);
        }
        atomicAdd(&agg[(size_t)d * HDIM + lane], acc);
    }
}

// ---------------- mean + relu (in place) ----------------
__global__ void finalize_kernel(float* __restrict__ agg, const float* __restrict__ deg) {
    int i = blockIdx.x * blockDim.x + threadIdx.x;
    if (i >= N_NODES * HDIM) return;
    int n = i >> 6;  // node index (HDIM == 64)
    float inv = 1.0f / fmaxf(deg[n], 1.0f);
    float v = agg[i] * inv;
    agg[i] = v > 0.f ? v : 0.f;
}

extern "C" void kernel_launch(void* const* d_in, const int* in_sizes, int n_in,
                              void* d_out, int out_size, void* d_ws, size_t ws_size,
                              hipStream_t stream) {
    const float* h = (const float*)d_in[0];
    const int* src = (const int*)d_in[1];
    const int* dst = (const int*)d_in[2];
    const int* rel = (const int*)d_in[3];
    const float* W1 = (const float*)d_in[4];
    const float* W2 = (const float*)d_in[5];
    float* out = (float*)d_out;

    // ---- workspace layout (all 16B-aligned) ----
    char* w = (char*)d_ws;
    int* cnt = (int*)w;            // 32 ints
    int* ofs = cnt + 32;           // 32 ints
    int* ssrc = (int*)(w + 256);   // N_EDGES
    int* sdst = ssrc + N_EDGES;    // N_EDGES
    int* srel = sdst + N_EDGES;    // N_EDGES
    float* deg = (float*)(srel + N_EDGES);  // N_NODES
    float* h1 = deg + N_NODES;              // N_NODES*HDIM

    // ---- zero what must be zero every call ----
    hipMemsetAsync(cnt, 0, 64 * sizeof(int), stream);
    hipMemsetAsync(deg, 0, N_NODES * sizeof(float), stream);
    hipMemsetAsync(h1, 0, (size_t)N_NODES * HDIM * sizeof(float), stream);
    hipMemsetAsync(out, 0, (size_t)N_NODES * HDIM * sizeof(float), stream);

    // ---- sort edges by relation (counting sort) + degree ----
    hist_kernel<<<512, 256, 0, stream>>>(rel, cnt);
    scan_kernel<<<1, 64, 0, stream>>>(cnt, ofs);
    scatter_kernel<<<1024, 256, 0, stream>>>(src, dst, rel, ofs, ssrc, sdst, srel, deg);

    const int EDGE_BLOCKS = 2048;  // 8192 waves, ~147 edges/wave
    const int FIN_BLOCKS = (N_NODES * HDIM + 255) / 256;

    // ---- layer 1: h -> h1 ----
    edge_kernel<<<EDGE_BLOCKS, 256, 0, stream>>>(h, ssrc, sdst, srel, W1, h1);
    finalize_kernel<<<FIN_BLOCKS, 256, 0, stream>>>(h1, deg);

    // ---- layer 2: h1 -> out ----
    edge_kernel<<<EDGE_BLOCKS, 256, 0, stream>>>(h1, ssrc, sdst, srel, W2, out);
    finalize_kernel<<<FIN_BLOCKS, 256, 0, stream>>>(out, deg);
}

// Round 2
// 749.778 us; speedup vs baseline: 4.3980x; 4.3980x over previous
//
#include <hip/hip_runtime.h>

#define N_NODES 100000
#define N_EDGES 1200000
#define HDIM 64
#define NUM_RELS 24

// ---------------- histogram of rel (24 bins) ----------------
__global__ void hist_kernel(const int* __restrict__ rel, int* __restrict__ cnt) {
    __shared__ int lc[NUM_RELS];
    if (threadIdx.x < NUM_RELS) lc[threadIdx.x] = 0;
    __syncthreads();
    for (int i = blockIdx.x * blockDim.x + threadIdx.x; i < N_EDGES;
         i += gridDim.x * blockDim.x)
        atomicAdd(&lc[rel[i]], 1);
    __syncthreads();
    if (threadIdx.x < NUM_RELS) atomicAdd(&cnt[threadIdx.x], lc[threadIdx.x]);
}

// ---------------- exclusive scan of 24 bins (1 thread) ----------------
__global__ void scan_kernel(const int* __restrict__ cnt, int* __restrict__ ofs) {
    if (threadIdx.x == 0 && blockIdx.x == 0) {
        int acc = 0;
        for (int r = 0; r < NUM_RELS; ++r) { ofs[r] = acc; acc += cnt[r]; }
    }
}

// ---------------- two-level scatter into rel-sorted order + degree ----------------
// Per block: LDS histogram -> ONE global atomicAdd per bin to reserve a range
// -> LDS-atomic ranking -> coalesced-ish writes. Global atomics: 1024*24
// instead of 1.2M on 24 addresses.
__global__ __launch_bounds__(256) void scatter_kernel(
    const int* __restrict__ src, const int* __restrict__ dst,
    const int* __restrict__ rel, int* __restrict__ ofs,
    int* __restrict__ ssrc, int* __restrict__ sdst,
    int* __restrict__ srel, float* __restrict__ deg) {
    __shared__ int lc[NUM_RELS];
    __shared__ int base[NUM_RELS];

    const int per = (N_EDGES + gridDim.x - 1) / gridDim.x;
    const int lo = blockIdx.x * per;
    int hi = lo + per;
    if (hi > N_EDGES) hi = N_EDGES;

    if (threadIdx.x < NUM_RELS) lc[threadIdx.x] = 0;
    __syncthreads();

    for (int i = lo + threadIdx.x; i < hi; i += blockDim.x)
        atomicAdd(&lc[rel[i]], 1);
    __syncthreads();

    if (threadIdx.x < NUM_RELS) {
        base[threadIdx.x] = atomicAdd(&ofs[threadIdx.x], lc[threadIdx.x]);
        lc[threadIdx.x] = 0;
    }
    __syncthreads();

    for (int i = lo + threadIdx.x; i < hi; i += blockDim.x) {
        int r = rel[i];
        int d = dst[i];
        int p = base[r] + atomicAdd(&lc[r], 1);
        ssrc[p] = src[i];
        sdst[p] = d;
        srel[p] = r;
        atomicAdd(&deg[d], 1.0f);
    }
}

// ---------------- per-edge transform + scatter-add ----------------
// One wave per contiguous chunk of rel-sorted edges. Lane j keeps column j of
// W[r] in registers (64 VGPR); h[src] is wave-uniform (broadcast float4 loads).
__global__ __launch_bounds__(256) void edge_kernel(
    const float* __restrict__ hin, const int* __restrict__ ssrc,
    const int* __restrict__ sdst, const int* __restrict__ srel,
    const float* __restrict__ W, float* __restrict__ agg) {
    const int lane = threadIdx.x & 63;
    const int wid = blockIdx.x * (blockDim.x >> 6) + (threadIdx.x >> 6);
    const int nw = gridDim.x * (blockDim.x >> 6);
    const int per = (N_EDGES + nw - 1) / nw;
    int lo = wid * per;
    int hi = lo + per;
    if (hi > N_EDGES) hi = N_EDGES;
    if (lo >= hi) return;

    float wcol[HDIM];
    int cur_r = -1;
    for (int e = lo; e < hi; ++e) {
        int r = __builtin_amdgcn_readfirstlane(srel[e]);
        int s = __builtin_amdgcn_readfirstlane(ssrc[e]);
        int d = __builtin_amdgcn_readfirstlane(sdst[e]);
        if (r != cur_r) {  // wave-uniform branch; ~1 reload per chunk
            cur_r = r;
            const float* wp = W + (size_t)r * (HDIM * HDIM) + lane;
#pragma unroll
            for (int k = 0; k < HDIM; ++k) wcol[k] = wp[(size_t)k * HDIM];
        }
        const float4* hp = (const float4*)(hin + (size_t)s * HDIM);
        float acc = 0.f;
#pragma unroll
        for (int q = 0; q < HDIM / 4; ++q) {
            float4 hv = hp[q];
            acc = fmaf(hv.x, wcol[4 * q + 0], acc);
            acc = fmaf(hv.y, wcol[4 * q + 1], acc);
            acc = fmaf(hv.z, wcol[4 * q + 2], acc);
            acc = fmaf(hv.w, wcol[4 * q + 3], acc);
        }
        atomicAdd(&agg[(size_t)d * HDIM + lane], acc);
    }
}

// ---------------- mean + relu (in place) ----------------
__global__ void finalize_kernel(float* __restrict__ agg, const float* __restrict__ deg) {
    int i = blockIdx.x * blockDim.x + threadIdx.x;
    if (i >= N_NODES * HDIM) return;
    int n = i >> 6;  // node index (HDIM == 64)
    float inv = 1.0f / fmaxf(deg[n], 1.0f);
    float v = agg[i] * inv;
    agg[i] = v > 0.f ? v : 0.f;
}

extern "C" void kernel_launch(void* const* d_in, const int* in_sizes, int n_in,
                              void* d_out, int out_size, void* d_ws, size_t ws_size,
                              hipStream_t stream) {
    const float* h = (const float*)d_in[0];
    const int* src = (const int*)d_in[1];
    const int* dst = (const int*)d_in[2];
    const int* rel = (const int*)d_in[3];
    const float* W1 = (const float*)d_in[4];
    const float* W2 = (const float*)d_in[5];
    float* out = (float*)d_out;

    // ---- workspace layout (all 16B-aligned) ----
    char* w = (char*)d_ws;
    int* cnt = (int*)w;            // 32 ints
    int* ofs = cnt + 32;           // 32 ints
    int* ssrc = (int*)(w + 256);   // N_EDGES
    int* sdst = ssrc + N_EDGES;    // N_EDGES
    int* srel = sdst + N_EDGES;    // N_EDGES
    float* deg = (float*)(srel + N_EDGES);  // N_NODES
    float* h1 = deg + N_NODES;              // N_NODES*HDIM

    // ---- zero what must be zero every call ----
    hipMemsetAsync(cnt, 0, 64 * sizeof(int), stream);
    hipMemsetAsync(deg, 0, N_NODES * sizeof(float), stream);
    hipMemsetAsync(h1, 0, (size_t)N_NODES * HDIM * sizeof(float), stream);
    hipMemsetAsync(out, 0, (size_t)N_NODES * HDIM * sizeof(float), stream);

    // ---- sort edges by relation (counting sort) + degree ----
    hist_kernel<<<512, 256, 0, stream>>>(rel, cnt);
    scan_kernel<<<1, 64, 0, stream>>>(cnt, ofs);
    scatter_kernel<<<1024, 256, 0, stream>>>(src, dst, rel, ofs, ssrc, sdst, srel, deg);

    const int EDGE_BLOCKS = 2048;  // 8192 waves, ~147 edges/wave
    const int FIN_BLOCKS = (N_NODES * HDIM + 255) / 256;

    // ---- layer 1: h -> h1 ----
    edge_kernel<<<EDGE_BLOCKS, 256, 0, stream>>>(h, ssrc, sdst, srel, W1, h1);
    finalize_kernel<<<FIN_BLOCKS, 256, 0, stream>>>(h1, deg);

    // ---- layer 2: h1 -> out ----
    edge_kernel<<<EDGE_BLOCKS, 256, 0, stream>>>(h1, ssrc, sdst, srel, W2, out);
    finalize_kernel<<<FIN_BLOCKS, 256, 0, stream>>>(out, deg);
}